// Round 1
// 167.104 us; speedup vs baseline: 1.0730x; 1.0730x over previous
//
#include <hip/hip_runtime.h>
#include <stdint.h>

#define NN 4096
#define FF 256
#define HH 4
#define DD 64
#define NEG 0.2f
#define LOG2E 1.4426950408889634f

#define ITILE 32
#define NSLICE 8
#define JRANGE (NN / NSLICE)   // 512
#define CJ 64

typedef __attribute__((ext_vector_type(8))) short short8;
typedef __attribute__((ext_vector_type(4))) float f32x4;
typedef __attribute__((ext_vector_type(16))) float f32x16;

__device__ __forceinline__ uint16_t bf16_rh(float f) {
    uint32_t u = __float_as_uint(f);
    return (uint16_t)((u + 0x8000u) >> 16);
}

// ---------------- convert x, W to bf16; zero pden (memset fused) ------------
__global__ __launch_bounds__(256) void cvt_inputs(const float* __restrict__ x,
                                                  const float* __restrict__ W,
                                                  uint16_t* __restrict__ xb,
                                                  uint16_t* __restrict__ Wb,
                                                  float4* __restrict__ pden4) {
    const int idx = blockIdx.x * 256 + threadIdx.x;  // float4 index
    const int nx = NN * FF / 4;
    const int nw = FF * FF / 4;
    if (idx < NN * HH / 4) pden4[idx] = make_float4(0.f, 0.f, 0.f, 0.f);
    if (idx < nx) {
        float4 v = ((const float4*)x)[idx];
        ushort4 o;
        o.x = bf16_rh(v.x); o.y = bf16_rh(v.y);
        o.z = bf16_rh(v.z); o.w = bf16_rh(v.w);
        ((ushort4*)xb)[idx] = o;
    } else if (idx < nx + nw) {
        int k = idx - nx;
        float4 v = ((const float4*)W)[k];
        ushort4 o;
        o.x = bf16_rh(v.x); o.y = bf16_rh(v.y);
        o.z = bf16_rh(v.z); o.w = bf16_rh(v.w);
        ((ushort4*)Wb)[k] = o;
    }
}

// ---------------- h = x @ W^T via bf16 MFMA (fp32 acc/out) ------------------
__global__ __launch_bounds__(256) void gemm_h(const uint16_t* __restrict__ xb,
                                              const uint16_t* __restrict__ Wb,
                                              float* __restrict__ h) {
    const int tid = threadIdx.x;
    const int w = tid >> 6, l = tid & 63;
    const int m = l & 15, q = l >> 4;             // 16x16x32: m=l&15, k=q*8+j
    const int i0 = blockIdx.x * 64 + w * 16;
    const int f0 = blockIdx.y * 64;
    f32x4 acc[4];
#pragma unroll
    for (int n = 0; n < 4; n++)
#pragma unroll
        for (int r = 0; r < 4; r++) acc[n][r] = 0.f;
    const uint16_t* arow = xb + (size_t)(i0 + m) * FF + q * 8;
#pragma unroll
    for (int k0 = 0; k0 < FF; k0 += 32) {
        short8 af = *(const short8*)(arow + k0);
#pragma unroll
        for (int n = 0; n < 4; n++) {
            short8 bf = *(const short8*)(Wb + (size_t)(f0 + n * 16 + m) * FF + k0 + q * 8);
            acc[n] = __builtin_amdgcn_mfma_f32_16x16x32_bf16(af, bf, acc[n], 0, 0, 0);
        }
    }
#pragma unroll
    for (int n = 0; n < 4; n++)
#pragma unroll
        for (int r = 0; r < 4; r++) {
            int row = q * 4 + r;                  // C: col=l&15, row=q*4+reg
            h[(size_t)(i0 + row) * FF + f0 + n * 16 + m] = acc[n][r];
        }
}

// ---------------- s,t (pre-scaled by log2e) + bf16 transpose H_T ------------
// block: 64 nodes; thread (r,h) does the full 64-d dot for (node,head).
// H_T store phase: 8 consecutive lanes write one contiguous 128B row run.
__global__ __launch_bounds__(256) void st_trans(const float* __restrict__ h,
                                                const float* __restrict__ a_src,
                                                const float* __restrict__ a_dst,
                                                float* __restrict__ s,
                                                float* __restrict__ T_T,
                                                uint16_t* __restrict__ H_T) {
    __shared__ uint16_t stage[64][258];
    const int tid = threadIdx.x;
    const int r = tid >> 2, hh = tid & 3;
    const int i0 = blockIdx.x * 64;
    const float* hrow = h + (size_t)(i0 + r) * FF + hh * DD;
    const float* as = a_src + hh * DD;
    const float* ad = a_dst + hh * DD;
    float vs = 0.f, vd = 0.f;
#pragma unroll
    for (int d4 = 0; d4 < DD; d4 += 4) {
        float4 hv = *(const float4*)(hrow + d4);
        float4 av = *(const float4*)(as + d4);
        float4 dv = *(const float4*)(ad + d4);
        vs += hv.x * av.x + hv.y * av.y + hv.z * av.z + hv.w * av.w;
        vd += hv.x * dv.x + hv.y * dv.y + hv.z * dv.z + hv.w * dv.w;
        uint32_t w0 = (uint32_t)bf16_rh(hv.x) | ((uint32_t)bf16_rh(hv.y) << 16);
        uint32_t w1 = (uint32_t)bf16_rh(hv.z) | ((uint32_t)bf16_rh(hv.w) << 16);
        *(uint32_t*)&stage[r][hh * DD + d4]     = w0;
        *(uint32_t*)&stage[r][hh * DD + d4 + 2] = w1;
    }
    s[(size_t)(i0 + r) * HH + hh] = vs * LOG2E;   // log2-domain scores
    T_T[(size_t)hh * NN + i0 + r] = vd * LOG2E;
    __syncthreads();
    const int wv = tid >> 6, ln = tid & 63;
    const int r8 = ln >> 3, ls = ln & 7;          // 8 lanes cover one f-row
#pragma unroll
    for (int pass = 0; pass < 8; pass++) {
        const int f = wv * 64 + pass * 8 + r8;
        union { uint16_t u[8]; short8 v; } o;
#pragma unroll
        for (int j = 0; j < 8; j++) o.u[j] = stage[ls * 8 + j][f];
        *(short8*)(H_T + (size_t)f * NN + i0 + ls * 8) = o.v;   // 128B/8 lanes
    }
}

// ---------------- fused scores -> exp2 -> P (A-frag regs) -> MFMA PV --------
// block: 32 i x 512 j-slice; wave w = head w. adj chunk (64 j) staged via LDS
// with REGISTER PREFETCH of the next chunk so the HBM latency hides under the
// 4 kk compute steps. Scores in log2-domain (no max-sub needed: args bounded).
__global__ __launch_bounds__(256, 4) void gat_main(
    const float* __restrict__ adj, const uint16_t* __restrict__ H_T,
    const float* __restrict__ s, const float* __restrict__ T_T,
    float* __restrict__ pden, uint16_t* __restrict__ part) {
    __shared__ float adj_s[CJ][ITILE + 1];        // transposed [j][i], pad->conflict-free
    const int tid = threadIdx.x;
    const int w = tid >> 6, l = tid & 63;
    const int m = l & 31, q = l >> 5;             // 32x32x16: m=l&31, k=q*8+j
    const int i0 = blockIdx.x * ITILE;
    const int sl = blockIdx.y;
    const int jb = sl * JRANGE;

    const float sS = s[(size_t)(i0 + m) * HH + w];  // already *log2e
    const float sB = NEG * sS;
    float den = 0.f;
    f32x16 acc0, acc1;
#pragma unroll
    for (int r = 0; r < 16; r++) { acc0[r] = 0.f; acc1[r] = 0.f; }
    const float* trow = T_T + (size_t)w * NN;
    const uint16_t* b0row = H_T + (size_t)(w * DD + m) * NN;
    const uint16_t* b1row = H_T + (size_t)(w * DD + 32 + m) * NN;

    // staging geometry: thread stages adj[i0+is][jc+j8 .. +7] (32B)
    const int is = tid >> 3, j8 = (tid & 7) * 8;
    const float* arow = adj + (size_t)(i0 + is) * NN + j8;
    float4 pre0 = *(const float4*)(arow + jb);
    float4 pre1 = *(const float4*)(arow + jb + 4);

    for (int jc = jb; jc < jb + JRANGE; jc += CJ) {
        __syncthreads();                          // prev compute done with adj_s
        adj_s[j8 + 0][is] = pre0.x; adj_s[j8 + 1][is] = pre0.y;
        adj_s[j8 + 2][is] = pre0.z; adj_s[j8 + 3][is] = pre0.w;
        adj_s[j8 + 4][is] = pre1.x; adj_s[j8 + 5][is] = pre1.y;
        adj_s[j8 + 6][is] = pre1.z; adj_s[j8 + 7][is] = pre1.w;
        if (jc + CJ < jb + JRANGE) {              // prefetch next chunk (in flight
            pre0 = *(const float4*)(arow + jc + CJ);      //  across the compute phase)
            pre1 = *(const float4*)(arow + jc + CJ + 4);
        }
        __syncthreads();                          // adj_s ready
#pragma unroll
        for (int kk = 0; kk < CJ; kk += 16) {
            const int jg = jc + kk + q * 8;       // this lane's first j (global)
            float4 t0 = *(const float4*)(trow + jg);
            float4 t1 = *(const float4*)(trow + jg + 4);
            float tt[8] = {t0.x, t0.y, t0.z, t0.w, t1.x, t1.y, t1.z, t1.w};
            uint32_t pk[4];
#pragma unroll
            for (int jj = 0; jj < 8; jj += 2) {
                float av0 = adj_s[kk + q * 8 + jj][m];
                float av1 = adj_s[kk + q * 8 + jj + 1][m];
                // lrelu in log2 domain: max(S+T, 0.2*(S+T)) ; exp2 direct
                float x10 = sS + tt[jj],     x20 = fmaf(NEG, tt[jj], sB);
                float x11 = sS + tt[jj + 1], x21 = fmaf(NEG, tt[jj + 1], sB);
                float lr0 = fmaxf(x10, x20), lr1 = fmaxf(x11, x21);
                float e0, e1;
                asm("v_exp_f32 %0, %1" : "=v"(e0) : "v"(lr0));
                asm("v_exp_f32 %0, %1" : "=v"(e1) : "v"(lr1));
                e0 = (av0 > 0.f) ? e0 : 0.f;
                e1 = (av1 > 0.f) ? e1 : 0.f;
                den += e0 + e1;
                float p0 = e0 * av0, p1 = e1 * av1;
                uint32_t u0 = __float_as_uint(p0) + 0x8000u;
                uint32_t u1 = __float_as_uint(p1) + 0x8000u;
                pk[jj >> 1] = (u0 >> 16) | (u1 & 0xffff0000u);
            }
            union { uint32_t u[4]; short8 v; } afu;
#pragma unroll
            for (int c = 0; c < 4; c++) afu.u[c] = pk[c];
            short8 bf0 = *(const short8*)(b0row + jg);
            short8 bf1 = *(const short8*)(b1row + jg);
            acc0 = __builtin_amdgcn_mfma_f32_32x32x16_bf16(afu.v, bf0, acc0, 0, 0, 0);
            acc1 = __builtin_amdgcn_mfma_f32_32x32x16_bf16(afu.v, bf1, acc1, 0, 0, 0);
        }
    }
    den += __shfl_down(den, 32, 64);              // lanes l and l+32 share m
    if (l < 32) atomicAdd(&pden[(size_t)(i0 + m) * HH + w], den);
    uint16_t* pbase = part + (size_t)sl * NN * FF;
#pragma unroll
    for (int reg = 0; reg < 16; reg++) {
        int row = (reg & 3) + 8 * (reg >> 2) + 4 * q;  // C: col=l&31, verified m74
        pbase[(size_t)(i0 + row) * FF + w * DD + m]      = bf16_rh(acc0[reg]);
        pbase[(size_t)(i0 + row) * FF + w * DD + 32 + m] = bf16_rh(acc1[reg]);
    }
}

// ---------------- sum slice partials, divide by denom -----------------------
__global__ __launch_bounds__(256) void finalize(const uint16_t* __restrict__ part,
                                                const float* __restrict__ pden,
                                                float* __restrict__ out) {
    const int i = blockIdx.x, f = threadIdx.x;
    float sum = 0.f;
#pragma unroll
    for (int sl = 0; sl < NSLICE; sl++) {
        uint16_t v = part[(size_t)sl * NN * FF + (size_t)i * FF + f];
        sum += __uint_as_float(((uint32_t)v) << 16);
    }
    float d = pden[(size_t)i * HH + (f >> 6)];
    out[(size_t)i * FF + f] = (d > 0.f) ? sum / d : 0.f;
}

extern "C" void kernel_launch(void* const* d_in, const int* in_sizes, int n_in,
                              void* d_out, int out_size, void* d_ws, size_t ws_size,
                              hipStream_t stream) {
    const float* x     = (const float*)d_in[0];
    const float* adj   = (const float*)d_in[1];
    const float* W     = (const float*)d_in[2];
    const float* a_src = (const float*)d_in[3];
    const float* a_dst = (const float*)d_in[4];
    float* out = (float*)d_out;

    char* ws = (char*)d_ws;
    float*    h    = (float*)ws;                                   // 4 MB
    uint16_t* H_T  = (uint16_t*)(ws + (4u << 20));                 // 2 MB
    uint16_t* xb   = (uint16_t*)(ws + (6u << 20));                 // 2 MB
    uint16_t* Wb   = (uint16_t*)(ws + (8u << 20));                 // 128 KB
    float*    s    = (float*)(ws + (8u << 20) + (128u << 10));     // 64 KB
    float*    T_T  = s + (size_t)NN * HH;                          // 64 KB
    float*    pden = T_T + (size_t)HH * NN;                        // 64 KB
    uint16_t* part = (uint16_t*)(ws + (9u << 20));                 // 16 MB

    cvt_inputs<<<(NN * FF / 4 + FF * FF / 4 + 255) / 256, 256, 0, stream>>>(
        x, W, xb, Wb, (float4*)pden);
    gemm_h<<<dim3(NN / 64, FF / 64), 256, 0, stream>>>(xb, Wb, h);
    st_trans<<<NN / 64, 256, 0, stream>>>(h, a_src, a_dst, s, T_T, H_T);
    gat_main<<<dim3(NN / ITILE, NSLICE), 256, 0, stream>>>(adj, H_T, s, T_T, pden, part);
    finalize<<<NN, 256, 0, stream>>>(part, pden, out);
}

// Round 2
// 161.769 us; speedup vs baseline: 1.1084x; 1.0330x over previous
//
#include <hip/hip_runtime.h>
#include <stdint.h>

#define NN 4096
#define FF 256
#define HH 4
#define DD 64
#define NEG 0.2f
#define LOG2E 1.4426950408889634f

#define ITILE 32
#define CJ 64

typedef __attribute__((ext_vector_type(8))) short short8;
typedef __attribute__((ext_vector_type(4))) float f32x4;
typedef __attribute__((ext_vector_type(16))) float f32x16;

__device__ __forceinline__ uint16_t bf16_rh(float f) {
    uint32_t u = __float_as_uint(f);
    return (uint16_t)((u + 0x8000u) >> 16);
}

// ---------------- convert x, W to bf16; zero pden (memset fused) ------------
__global__ __launch_bounds__(256) void cvt_inputs(const float* __restrict__ x,
                                                  const float* __restrict__ W,
                                                  uint16_t* __restrict__ xb,
                                                  uint16_t* __restrict__ Wb,
                                                  float4* __restrict__ pden4) {
    const int idx = blockIdx.x * 256 + threadIdx.x;  // float4 index
    const int nx = NN * FF / 4;
    const int nw = FF * FF / 4;
    if (idx < NN * HH / 4) pden4[idx] = make_float4(0.f, 0.f, 0.f, 0.f);
    if (idx < nx) {
        float4 v = ((const float4*)x)[idx];
        ushort4 o;
        o.x = bf16_rh(v.x); o.y = bf16_rh(v.y);
        o.z = bf16_rh(v.z); o.w = bf16_rh(v.w);
        ((ushort4*)xb)[idx] = o;
    } else if (idx < nx + nw) {
        int k = idx - nx;
        float4 v = ((const float4*)W)[k];
        ushort4 o;
        o.x = bf16_rh(v.x); o.y = bf16_rh(v.y);
        o.z = bf16_rh(v.z); o.w = bf16_rh(v.w);
        ((ushort4*)Wb)[k] = o;
    }
}

// ---------------- h = x @ W^T (bf16 MFMA) + FUSED s,t dots + H_T transpose --
// grid (NN/64, FF/64): blockIdx.y is exactly one head (64 f = one D-range),
// so the per-(i,head) dot over f completes inside the block: reduce acc over
// n in-lane, then over m via 16-lane shfl_xor. H_T written straight from the
// accumulator fragments (ushort4 per n). The h array never exists in memory.
__global__ __launch_bounds__(256) void gemm_h(const uint16_t* __restrict__ xb,
                                              const uint16_t* __restrict__ Wb,
                                              const float* __restrict__ a_src,
                                              const float* __restrict__ a_dst,
                                              float* __restrict__ s,
                                              float* __restrict__ T_T,
                                              uint16_t* __restrict__ H_T) {
    const int tid = threadIdx.x;
    const int w = tid >> 6, l = tid & 63;
    const int m = l & 15, q = l >> 4;             // 16x16x32: m=l&15, k=q*8+j
    const int i0 = blockIdx.x * 64 + w * 16;
    const int f0 = blockIdx.y * 64;
    const int hh = blockIdx.y;                    // head index
    f32x4 acc[4];
#pragma unroll
    for (int n = 0; n < 4; n++)
#pragma unroll
        for (int r = 0; r < 4; r++) acc[n][r] = 0.f;
    const uint16_t* arow = xb + (size_t)(i0 + m) * FF + q * 8;
#pragma unroll
    for (int k0 = 0; k0 < FF; k0 += 32) {
        short8 af = *(const short8*)(arow + k0);
#pragma unroll
        for (int n = 0; n < 4; n++) {
            short8 bf = *(const short8*)(Wb + (size_t)(f0 + n * 16 + m) * FF + k0 + q * 8);
            acc[n] = __builtin_amdgcn_mfma_f32_16x16x32_bf16(af, bf, acc[n], 0, 0, 0);
        }
    }
    // ---- fused epilogue: s,t dots (log2-scaled) ----
    const float* as = a_src + hh * DD;
    const float* ad = a_dst + hh * DD;
    float av[4], dv[4];
#pragma unroll
    for (int n = 0; n < 4; n++) { av[n] = as[n * 16 + m]; dv[n] = ad[n * 16 + m]; }
#pragma unroll
    for (int r = 0; r < 4; r++) {
        float vs = 0.f, vd = 0.f;
#pragma unroll
        for (int n = 0; n < 4; n++) {
            vs = fmaf(acc[n][r], av[n], vs);
            vd = fmaf(acc[n][r], dv[n], vd);
        }
#pragma unroll
        for (int off = 1; off < 16; off <<= 1) {  // reduce across m (lanes q*16+0..15)
            vs += __shfl_xor(vs, off, 64);
            vd += __shfl_xor(vd, off, 64);
        }
        if (m == 0) {
            const int i = i0 + q * 4 + r;         // C: col=l&15 -> f, row=q*4+r -> i
            s[(size_t)i * HH + hh] = vs * LOG2E;  // log2-domain scores
            T_T[(size_t)hh * NN + i] = vd * LOG2E;
        }
    }
    // ---- fused epilogue: bf16 transposed H_T[f][i] ----
#pragma unroll
    for (int n = 0; n < 4; n++) {
        ushort4 o;
        o.x = bf16_rh(acc[n][0]); o.y = bf16_rh(acc[n][1]);
        o.z = bf16_rh(acc[n][2]); o.w = bf16_rh(acc[n][3]);
        *(ushort4*)(H_T + (size_t)(f0 + n * 16 + m) * NN + i0 + q * 4) = o;
    }
}

// ---------------- fused scores -> exp2 -> P (A-frag regs) -> MFMA PV --------
// block: 32 i x (NN/NS) j-slice; wave w = head w. adj chunk (64 j) staged via
// LDS with register prefetch of the next chunk. Scores in log2-domain.
// XCD-aware swizzle: blocks sharing a j-slice (same H_T columns) land on the
// same XCD so the 128KB H_T slice stays L2-hot.
template<int NS>
__global__ __launch_bounds__(256, 4) void gat_main(
    const float* __restrict__ adj, const uint16_t* __restrict__ H_T,
    const float* __restrict__ s, const float* __restrict__ T_T,
    float* __restrict__ pden, uint16_t* __restrict__ part) {
    constexpr int JR = NN / NS;
    __shared__ float adj_s[CJ][ITILE + 1];
    const int tid = threadIdx.x;
    const int w = tid >> 6, l = tid & 63;
    const int m = l & 31, q = l >> 5;             // 32x32x16: m=l&31, k=q*8+j
    // bijective XCD swizzle (nwg % 8 == 0)
    constexpr int NWG = (NN / ITILE) * NS;
    const int orig = blockIdx.y * (NN / ITILE) + blockIdx.x;
    const int swz = (orig & 7) * (NWG / 8) + (orig >> 3);
    const int i0 = (swz & (NN / ITILE - 1)) * ITILE;
    const int sl = swz / (NN / ITILE);
    const int jb = sl * JR;

    const float sS = s[(size_t)(i0 + m) * HH + w];  // already *log2e
    const float sB = NEG * sS;
    float den = 0.f;
    f32x16 acc0, acc1;
#pragma unroll
    for (int r = 0; r < 16; r++) { acc0[r] = 0.f; acc1[r] = 0.f; }
    const float* trow = T_T + (size_t)w * NN;
    const uint16_t* b0row = H_T + (size_t)(w * DD + m) * NN;
    const uint16_t* b1row = H_T + (size_t)(w * DD + 32 + m) * NN;

    // staging geometry: thread stages adj[i0+is][jc+j8 .. +7] (32B)
    const int is = tid >> 3, j8 = (tid & 7) * 8;
    const float* arow = adj + (size_t)(i0 + is) * NN + j8;
    float4 pre0 = *(const float4*)(arow + jb);
    float4 pre1 = *(const float4*)(arow + jb + 4);

    for (int jc = jb; jc < jb + JR; jc += CJ) {
        __syncthreads();                          // prev compute done with adj_s
        adj_s[j8 + 0][is] = pre0.x; adj_s[j8 + 1][is] = pre0.y;
        adj_s[j8 + 2][is] = pre0.z; adj_s[j8 + 3][is] = pre0.w;
        adj_s[j8 + 4][is] = pre1.x; adj_s[j8 + 5][is] = pre1.y;
        adj_s[j8 + 6][is] = pre1.z; adj_s[j8 + 7][is] = pre1.w;
        if (jc + CJ < jb + JR) {                  // prefetch next chunk
            pre0 = *(const float4*)(arow + jc + CJ);
            pre1 = *(const float4*)(arow + jc + CJ + 4);
        }
        __syncthreads();                          // adj_s ready
#pragma unroll
        for (int kk = 0; kk < CJ; kk += 16) {
            const int jg = jc + kk + q * 8;       // this lane's first j (global)
            float4 t0 = *(const float4*)(trow + jg);
            float4 t1 = *(const float4*)(trow + jg + 4);
            float tt[8] = {t0.x, t0.y, t0.z, t0.w, t1.x, t1.y, t1.z, t1.w};
            uint32_t pk[4];
#pragma unroll
            for (int jj = 0; jj < 8; jj += 2) {
                float av0 = adj_s[kk + q * 8 + jj][m];
                float av1 = adj_s[kk + q * 8 + jj + 1][m];
                // lrelu in log2 domain: max(S+T, 0.2*(S+T)); exp2 direct
                float x10 = sS + tt[jj],     x20 = fmaf(NEG, tt[jj], sB);
                float x11 = sS + tt[jj + 1], x21 = fmaf(NEG, tt[jj + 1], sB);
                float lr0 = fmaxf(x10, x20), lr1 = fmaxf(x11, x21);
                float e0, e1;
                asm("v_exp_f32 %0, %1" : "=v"(e0) : "v"(lr0));
                asm("v_exp_f32 %0, %1" : "=v"(e1) : "v"(lr1));
                e0 = (av0 > 0.f) ? e0 : 0.f;
                e1 = (av1 > 0.f) ? e1 : 0.f;
                den += e0 + e1;
                float p0 = e0 * av0, p1 = e1 * av1;
                uint32_t u0 = __float_as_uint(p0) + 0x8000u;
                uint32_t u1 = __float_as_uint(p1) + 0x8000u;
                pk[jj >> 1] = (u0 >> 16) | (u1 & 0xffff0000u);
            }
            union { uint32_t u[4]; short8 v; } afu;
#pragma unroll
            for (int c = 0; c < 4; c++) afu.u[c] = pk[c];
            short8 bf0 = *(const short8*)(b0row + jg);
            short8 bf1 = *(const short8*)(b1row + jg);
            acc0 = __builtin_amdgcn_mfma_f32_32x32x16_bf16(afu.v, bf0, acc0, 0, 0, 0);
            acc1 = __builtin_amdgcn_mfma_f32_32x32x16_bf16(afu.v, bf1, acc1, 0, 0, 0);
        }
    }
    den += __shfl_down(den, 32, 64);              // lanes l and l+32 share m
    if (l < 32) atomicAdd(&pden[(size_t)(i0 + m) * HH + w], den);
    uint16_t* pbase = part + (size_t)sl * NN * FF;
#pragma unroll
    for (int reg = 0; reg < 16; reg++) {
        int row = (reg & 3) + 8 * (reg >> 2) + 4 * q;  // C: col=l&31, verified m74
        pbase[(size_t)(i0 + row) * FF + w * DD + m]      = bf16_rh(acc0[reg]);
        pbase[(size_t)(i0 + row) * FF + w * DD + 32 + m] = bf16_rh(acc1[reg]);
    }
}

// ---------------- sum slice partials, divide by denom -----------------------
template<int NS>
__global__ __launch_bounds__(256) void finalize(const uint16_t* __restrict__ part,
                                                const float* __restrict__ pden,
                                                float* __restrict__ out) {
    const int i = blockIdx.x, f = threadIdx.x;
    float sum = 0.f;
#pragma unroll
    for (int sl = 0; sl < NS; sl++) {
        uint16_t v = part[(size_t)sl * NN * FF + (size_t)i * FF + f];
        sum += __uint_as_float(((uint32_t)v) << 16);
    }
    float d = pden[(size_t)i * HH + (f >> 6)];
    out[(size_t)i * FF + f] = (d > 0.f) ? sum / d : 0.f;
}

extern "C" void kernel_launch(void* const* d_in, const int* in_sizes, int n_in,
                              void* d_out, int out_size, void* d_ws, size_t ws_size,
                              hipStream_t stream) {
    const float* x     = (const float*)d_in[0];
    const float* adj   = (const float*)d_in[1];
    const float* W     = (const float*)d_in[2];
    const float* a_src = (const float*)d_in[3];
    const float* a_dst = (const float*)d_in[4];
    float* out = (float*)d_out;

    char* ws = (char*)d_ws;
    uint16_t* H_T  = (uint16_t*)ws;                                // 2 MB
    uint16_t* xb   = (uint16_t*)(ws + (2u << 20));                 // 2 MB
    uint16_t* Wb   = (uint16_t*)(ws + (4u << 20));                 // 128 KB
    float*    s    = (float*)(ws + (4u << 20) + (128u << 10));     // 64 KB
    float*    T_T  = s + (size_t)NN * HH;                          // 64 KB
    float*    pden = T_T + (size_t)HH * NN;                        // 64 KB
    uint16_t* part = (uint16_t*)(ws + (5u << 20));                 // NS * 2 MB

    cvt_inputs<<<(NN * FF / 4 + FF * FF / 4 + 255) / 256, 256, 0, stream>>>(
        x, W, xb, Wb, (float4*)pden);
    gemm_h<<<dim3(NN / 64, FF / 64), 256, 0, stream>>>(xb, Wb, a_src, a_dst, s, T_T, H_T);
    if (ws_size >= (5u << 20) + (size_t)16 * NN * FF * sizeof(uint16_t)) {
        gat_main<16><<<dim3(NN / ITILE, 16), 256, 0, stream>>>(adj, H_T, s, T_T, pden, part);
        finalize<16><<<NN, 256, 0, stream>>>(part, pden, out);
    } else {
        gat_main<8><<<dim3(NN / ITILE, 8), 256, 0, stream>>>(adj, H_T, s, T_T, pden, part);
        finalize<8><<<NN, 256, 0, stream>>>(part, pden, out);
    }
}